// Round 7
// baseline (1227.923 us; speedup 1.0000x reference)
//
#include <hip/hip_runtime.h>

#define D 128
#define NP 65536
#define NV 1024

typedef __attribute__((ext_vector_type(8))) short short8;
typedef __attribute__((ext_vector_type(4))) float f32x4;

__device__ __forceinline__ unsigned short f2bf(float x) {
    unsigned int u = __builtin_bit_cast(unsigned int, x);
    u += 0x7FFFu + ((u >> 16) & 1u);          // round-to-nearest-even
    return (unsigned short)(u >> 16);
}
__device__ __forceinline__ unsigned int pack2bf(float a, float b) {
    return (unsigned int)f2bf(a) | ((unsigned int)f2bf(b) << 16);
}
__device__ __forceinline__ float bflo(unsigned int u) {
    return __builtin_bit_cast(float, u << 16);
}
__device__ __forceinline__ float bfhi(unsigned int u) {
    return __builtin_bit_cast(float, u & 0xFFFF0000u);
}

// ---------------- weight prep: W[k][n] f32 -> Wt[n][k] bf16 ----------------
__global__ __launch_bounds__(256)
void k_prep(const float* __restrict__ Wsp, const float* __restrict__ Wvw,
            const float* __restrict__ Wgl, const float* __restrict__ Wpr,
            unsigned short* __restrict__ o)
{
    const float* W = (blockIdx.x == 0) ? Wsp : (blockIdx.x == 1) ? Wvw
                   : (blockIdx.x == 2) ? Wgl : Wpr;
    unsigned short* Wt = o + (size_t)blockIdx.x * 16384;
    for (int c = threadIdx.x; c < 2048; c += 256) {
        int n = c >> 4, kb = (c & 15) * 8;
        unsigned int p[4];
        #pragma unroll
        for (int j = 0; j < 4; ++j)
            p[j] = pack2bf(W[(kb + 2 * j) * D + n], W[(kb + 2 * j + 1) * D + n]);
        *(short8*)(Wt + n * 128 + kb) = *(short8*)p;
    }
}

// ---------------- CSR build ----------------
__global__ __launch_bounds__(256)
void k_count(const int* __restrict__ vi, const int* __restrict__ pi,
             int* __restrict__ cp, int* __restrict__ cv, int nnz)
{
    int i = blockIdx.x * blockDim.x + threadIdx.x;
    int n = gridDim.x * blockDim.x;
    for (int e = i; e < nnz; e += n) {
        atomicAdd(&cp[pi[e]], 1);
        atomicAdd(&cv[vi[e]], 1);
    }
}

__global__ __launch_bounds__(256)
void k_scanA(const int* __restrict__ cp, int* __restrict__ bsum)
{
    __shared__ int l[256];
    int t = threadIdx.x;
    int4 c = ((const int4*)cp)[blockIdx.x * 256 + t];
    l[t] = c.x + c.y + c.z + c.w;
    __syncthreads();
    for (int d = 128; d > 0; d >>= 1) {
        if (t < d) l[t] += l[t + d];
        __syncthreads();
    }
    if (t == 0) bsum[blockIdx.x] = l[0];
}

__global__ __launch_bounds__(256)
void k_scanB(const int* __restrict__ bsum, int* __restrict__ bbase,
             int* __restrict__ cv, int* __restrict__ bv)
{
    __shared__ int l[256];
    int t = threadIdx.x;
    int own = (t < 64) ? bsum[t] : 0;
    l[t] = own;
    __syncthreads();
    for (int d = 1; d < 64; d <<= 1) {
        int u = (t >= d && t < 64) ? l[t - d] : 0;
        __syncthreads();
        if (t < 64) l[t] += u;
        __syncthreads();
    }
    if (t < 64) bbase[t] = l[t] - own;
    __syncthreads();
    int4 c = ((const int4*)cv)[t];
    int s4 = c.x + c.y + c.z + c.w;
    l[t] = s4;
    __syncthreads();
    for (int d = 1; d < 256; d <<= 1) {
        int u = (t >= d) ? l[t - d] : 0;
        __syncthreads();
        l[t] += u;
        __syncthreads();
    }
    int ex = l[t] - s4;
    int4 o; o.x = ex; o.y = ex + c.x; o.z = o.y + c.y; o.w = o.z + c.z;
    ((int4*)bv)[t] = o;
    ((int4*)cv)[t] = o;
}

__global__ __launch_bounds__(256)
void k_scanC(int* __restrict__ cp, int* __restrict__ bp, const int* __restrict__ bbase)
{
    __shared__ int l[256];
    int t = threadIdx.x;
    int i = blockIdx.x * 256 + t;
    int4 c = ((const int4*)cp)[i];
    int s4 = c.x + c.y + c.z + c.w;
    l[t] = s4;
    __syncthreads();
    for (int d = 1; d < 256; d <<= 1) {
        int u = (t >= d) ? l[t - d] : 0;
        __syncthreads();
        l[t] += u;
        __syncthreads();
    }
    int ex = l[t] - s4 + bbase[blockIdx.x];
    int4 o; o.x = ex; o.y = ex + c.x; o.z = o.y + c.y; o.w = o.z + c.z;
    ((int4*)bp)[i] = o;
    ((int4*)cp)[i] = o;
}

// ---------------- scatter + bf16 convert (sequential values read) ----------------
__global__ __launch_bounds__(256)
void k_scatter_cvt(const float* __restrict__ values, const int* __restrict__ vi,
                   const int* __restrict__ pi, int* __restrict__ curp,
                   int* __restrict__ curv, uint2* __restrict__ plv,
                   int* __restrict__ vlist, unsigned int* __restrict__ vbuf16, int nnz)
{
    int lane = threadIdx.x & 63, wv = threadIdx.x >> 6;
    int wave = blockIdx.x * 4 + wv, nw = gridDim.x * 4;
    for (int base = wave * 64; base < nnz; base += nw * 64) {
        int e = base + lane;
        int sp = 0;
        if (e < nnz) {
            int p = pi[e], v = vi[e];
            sp = atomicAdd(&curp[p], 1);
            int sv = atomicAdd(&curv[v], 1);
            plv[sp] = make_uint2((unsigned)e, (unsigned)v);
            vlist[sv] = sp;
        }
        int n = min(64, nnz - base);
        int j = 0;
        for (; j + 4 <= n; j += 4) {
            int s0 = __builtin_amdgcn_readlane(sp, j);
            int s1 = __builtin_amdgcn_readlane(sp, j + 1);
            int s2 = __builtin_amdgcn_readlane(sp, j + 2);
            int s3 = __builtin_amdgcn_readlane(sp, j + 3);
            float2 a = *(const float2*)(values + (size_t)(base + j) * D + lane * 2);
            float2 b = *(const float2*)(values + (size_t)(base + j + 1) * D + lane * 2);
            float2 c = *(const float2*)(values + (size_t)(base + j + 2) * D + lane * 2);
            float2 d = *(const float2*)(values + (size_t)(base + j + 3) * D + lane * 2);
            vbuf16[(size_t)s0 * 64 + lane] = pack2bf(a.x, a.y);
            vbuf16[(size_t)s1 * 64 + lane] = pack2bf(b.x, b.y);
            vbuf16[(size_t)s2 * 64 + lane] = pack2bf(c.x, c.y);
            vbuf16[(size_t)s3 * 64 + lane] = pack2bf(d.x, d.y);
        }
        for (; j < n; ++j) {
            int s0 = __builtin_amdgcn_readlane(sp, j);
            float2 a = *(const float2*)(values + (size_t)(base + j) * D + lane * 2);
            vbuf16[(size_t)s0 * 64 + lane] = pack2bf(a.x, a.y);
        }
    }
}

// ---------------- point sums: fully sequential over vbuf16 ----------------
__global__ __launch_bounds__(256)
void k_psum(const unsigned int* __restrict__ vbuf16, const int* __restrict__ pbase,
            const int* __restrict__ pend, unsigned int* __restrict__ mbuf,
            int* __restrict__ psp)
{
    int lane = threadIdx.x & 63, wv = threadIdx.x >> 6;
    int wave = blockIdx.x * 4 + wv, nw = gridDim.x * 4;
    for (int pt = wave; pt < NP; pt += nw) {
        int s = pbase[pt], e = pend[pt];
        float s0 = 0.f, s1 = 0.f;
        int i = s;
        for (; i + 4 <= e; i += 4) {
            unsigned int u0 = vbuf16[(size_t)i * 64 + lane];
            unsigned int u1 = vbuf16[(size_t)(i + 1) * 64 + lane];
            unsigned int u2 = vbuf16[(size_t)(i + 2) * 64 + lane];
            unsigned int u3 = vbuf16[(size_t)(i + 3) * 64 + lane];
            s0 += bflo(u0) + bflo(u1) + bflo(u2) + bflo(u3);
            s1 += bfhi(u0) + bfhi(u1) + bfhi(u2) + bfhi(u3);
        }
        for (; i < e; ++i) {
            unsigned int u = vbuf16[(size_t)i * 64 + lane];
            s0 += bflo(u); s1 += bfhi(u);
        }
        for (int q = s + lane; q < e; q += 64) psp[q] = pt;
        float inv = 1.f / fmaxf((float)(e - s), 1.f);
        mbuf[(size_t)pt * 64 + lane] = pack2bf(s0 * inv, s1 * inv);
    }
}

// ---------------- view sums from bf16 rows (8 rows in flight) ----------------
__global__ __launch_bounds__(256)
void k_vsum(const unsigned int* __restrict__ vbuf16, const int* __restrict__ vlist,
            const int* __restrict__ vbase, const int* __restrict__ vend,
            unsigned int* __restrict__ mbuf, float* __restrict__ gs)
{
    __shared__ float2 red[4][64];
    int lane = threadIdx.x & 63, wv = threadIdx.x >> 6;
    int v = blockIdx.x;
    int s = vbase[v], e = vend[v];
    float s0 = 0.f, s1 = 0.f;
    for (int b = s + wv * 64; b < e; b += 256) {
        int n = min(64, e - b);
        int idx = (lane < n) ? vlist[b + lane] : 0;
        int j = 0;
        for (; j + 8 <= n; j += 8) {
            unsigned int u[8];
            #pragma unroll
            for (int q = 0; q < 8; ++q) {
                int r = __builtin_amdgcn_readlane(idx, j + q);
                u[q] = vbuf16[(size_t)r * 64 + lane];
            }
            #pragma unroll
            for (int q = 0; q < 8; ++q) { s0 += bflo(u[q]); s1 += bfhi(u[q]); }
        }
        for (; j < n; ++j) {
            int r = __builtin_amdgcn_readlane(idx, j);
            unsigned int u = vbuf16[(size_t)r * 64 + lane];
            s0 += bflo(u); s1 += bfhi(u);
        }
    }
    red[wv][lane] = make_float2(s0, s1);
    __syncthreads();
    if (wv == 0) {
        float2 a = red[0][lane], b2 = red[1][lane], c = red[2][lane], d2 = red[3][lane];
        float t0 = a.x + b2.x + c.x + d2.x;
        float t1 = a.y + b2.y + c.y + d2.y;
        atomicAdd(&gs[lane * 2], t0);
        atomicAdd(&gs[lane * 2 + 1], t1);
        float inv = 1.f / fmaxf((float)(e - s), 1.f);
        mbuf[(size_t)(NP + v) * 64 + lane] = pack2bf(t0 * inv, t1 * inv);
    }
}

// ---------------- shared MFMA tile machinery ----------------
// LDS layout: bf16 [128 rows][128 k], byte addr = (row*256 + k*2) ^ ((row&7)<<4)

__device__ __forceinline__ void stage_bf16(const unsigned short* __restrict__ g,
                                           unsigned short* lds, int t)
{
    #pragma unroll
    for (int i = 0; i < 8; ++i) {
        int c = i * 256 + t;
        int row = c >> 4, kb = (c & 15) * 16;
        short8 v = *(const short8*)(g + row * 128 + (c & 15) * 8);
        *(short8*)&lds[((row * 256 + kb) ^ ((row & 7) << 4)) >> 1] = v;
    }
}

__device__ __forceinline__ void mfma_tile(const unsigned short* Al, const unsigned short* Bl,
                                          int lane, int w, f32x4 acc[8][2])
{
    int lr = lane & 15, lg = lane >> 4;
    #pragma unroll
    for (int kc = 0; kc < 4; ++kc) {
        int kb = kc * 64 + lg * 16;
        int bn0 = w * 32 + lr, bn1 = bn0 + 16;
        short8 b0 = *(const short8*)&Bl[((bn0 * 256 + kb) ^ ((bn0 & 7) << 4)) >> 1];
        short8 b1 = *(const short8*)&Bl[((bn1 * 256 + kb) ^ ((bn1 & 7) << 4)) >> 1];
        #pragma unroll
        for (int m = 0; m < 8; ++m) {
            int row = m * 16 + lr;
            short8 a = *(const short8*)&Al[((row * 256 + kb) ^ ((row & 7) << 4)) >> 1];
            acc[m][0] = __builtin_amdgcn_mfma_f32_16x16x32_bf16(a, b0, acc[m][0], 0, 0, 0);
            acc[m][1] = __builtin_amdgcn_mfma_f32_16x16x32_bf16(a, b1, acc[m][1], 0, 0, 0);
        }
    }
}

// ---------------- feature GEMM -> packed (c,c+16) uint rows ----------------
__global__ __launch_bounds__(256)
void k_featgemm(const unsigned int* __restrict__ mbuf, const unsigned short* __restrict__ Wt4,
                const float* __restrict__ bSp, const float* __restrict__ bVw,
                const float* __restrict__ bGl, const float* __restrict__ gs,
                float inv_nnz, unsigned int* __restrict__ fbp)
{
    __shared__ unsigned short Al[128 * 128];
    __shared__ unsigned short Bl[128 * 128];
    int t = threadIdx.x;
    int tile = blockIdx.x;   // 0..520
    const unsigned short* Wt; const float* bias; int rowbase; int vrows = 128;
    if (tile < 512)      { Wt = Wt4;             bias = bSp; rowbase = tile * 128; }
    else if (tile < 520) { Wt = Wt4 + 16384;     bias = bVw; rowbase = NP + (tile - 512) * 128; }
    else                 { Wt = Wt4 + 2 * 16384; bias = bGl; rowbase = NP + NV; vrows = 1; }
    stage_bf16(Wt, Bl, t);
    if (tile < 520) {
        stage_bf16((const unsigned short*)(mbuf + (size_t)rowbase * 64), Al, t);
    } else {
        #pragma unroll
        for (int i = 0; i < 8; ++i) {
            int c = i * 256 + t;
            int row = c >> 4, cb = (c & 15) * 8;
            unsigned int p[4] = {0u, 0u, 0u, 0u};
            if (row == 0) {
                #pragma unroll
                for (int j = 0; j < 4; ++j)
                    p[j] = pack2bf(gs[cb + 2 * j] * inv_nnz, gs[cb + 2 * j + 1] * inv_nnz);
            }
            *(short8*)&Al[((row * 256 + cb * 2) ^ ((row & 7) << 4)) >> 1] = *(short8*)p;
        }
    }
    __syncthreads();
    f32x4 acc[8][2] = {};
    int lane = t & 63, w = t >> 6;
    mfma_tile(Al, Bl, lane, w, acc);
    int lr = lane & 15, lg = lane >> 4;
    int c0 = w * 32 + lr, c1 = c0 + 16;
    float bb0 = 0.25f * bias[c0], bb1 = 0.25f * bias[c1];
    #pragma unroll
    for (int m = 0; m < 8; ++m)
        #pragma unroll
        for (int r = 0; r < 4; ++r) {
            int row = m * 16 + lg * 4 + r;
            if (row < vrows)
                fbp[(size_t)(rowbase + row) * 64 + w * 16 + lr] =
                    pack2bf(acc[m][0][r] * 0.25f + bb0, acc[m][1][r] * 0.25f + bb1);
        }
}

// ---------------- projection (plist order), full-line out writes ----------------
__global__ __launch_bounds__(256, 4)
void k_proj(const unsigned int* __restrict__ vbuf16, const uint2* __restrict__ plv,
            const int* __restrict__ psp, const unsigned short* __restrict__ WtPr,
            const float* __restrict__ bPr, const unsigned int* __restrict__ fbp,
            float* __restrict__ out, int nnz, int ntiles)
{
    __shared__ unsigned short Al[128 * 128];   // 32 KB; reused as f32 row staging
    __shared__ int eI[128], pI[128], vI[128];
    float* Alf = (float*)Al;
    int t = threadIdx.x, lane = t & 63, w = t >> 6;
    int lr = lane & 15, lg = lane >> 4;
    short8 Bf[4][2];
    #pragma unroll
    for (int kc = 0; kc < 4; ++kc) {
        Bf[kc][0] = *(const short8*)(WtPr + (w * 32 + lr) * 128 + kc * 32 + lg * 8);
        Bf[kc][1] = *(const short8*)(WtPr + (w * 32 + lr + 16) * 128 + kc * 32 + lg * 8);
    }
    int c0 = w * 32 + lr, c1 = c0 + 16;
    unsigned int gw = fbp[(size_t)(NP + NV) * 64 + w * 16 + lr];
    float base0 = 0.25f * bPr[c0] + bflo(gw);
    float base1 = 0.25f * bPr[c1] + bfhi(gw);
    const unsigned int* pfp = fbp;
    const unsigned int* vfp = fbp + (size_t)NP * 64;
    for (int tile = blockIdx.x; tile < ntiles; tile += gridDim.x) {
        int s = tile * 128;
        int vrows = min(128, nnz - s);
        stage_bf16((const unsigned short*)(vbuf16 + (size_t)s * 64), Al, t);
        if (t < 128) {
            int ok = t < vrows;
            uint2 q = ok ? plv[s + t] : make_uint2(0u, 0u);
            eI[t] = (int)q.x;
            vI[t] = (int)q.y;
            pI[t] = ok ? psp[s + t] : 0;
        }
        __syncthreads();
        f32x4 acc[8][2] = {};
        #pragma unroll
        for (int kc = 0; kc < 4; ++kc) {
            int kb = kc * 64 + lg * 16;
            #pragma unroll
            for (int m = 0; m < 8; ++m) {
                int row = m * 16 + lr;
                short8 a = *(const short8*)&Al[((row * 256 + kb) ^ ((row & 7) << 4)) >> 1];
                acc[m][0] = __builtin_amdgcn_mfma_f32_16x16x32_bf16(a, Bf[kc][0], acc[m][0], 0, 0, 0);
                acc[m][1] = __builtin_amdgcn_mfma_f32_16x16x32_bf16(a, Bf[kc][1], acc[m][1], 0, 0, 0);
            }
        }
        __syncthreads();   // all waves done reading Al (bf16) — safe to reuse as f32
        // epilogue: two 64-row halves staged in Alf, then coalesced full-line writes
        #pragma unroll
        for (int half = 0; half < 2; ++half) {
            #pragma unroll
            for (int mm = 0; mm < 4; ++mm) {
                int m = half * 4 + mm;
                #pragma unroll
                for (int r = 0; r < 4; ++r) {
                    int row = m * 16 + lg * 4 + r;      // global row (half*64 ..)
                    int lrow = row - half * 64;         // 0..63
                    int p = pI[row], vv = vI[row];
                    unsigned int pu = pfp[(size_t)p * 64 + w * 16 + lr];
                    unsigned int vu = vfp[(size_t)vv * 64 + w * 16 + lr];
                    float o0 = acc[m][0][r] * 0.25f + base0 + bflo(pu) + bflo(vu);
                    float o1 = acc[m][1][r] * 0.25f + base1 + bfhi(pu) + bfhi(vu);
                    int sw = lg << 4;                   // == ((row>>2)&3)<<4
                    Alf[lrow * 128 + (c0 ^ sw)] = o0;
                    Alf[lrow * 128 + (c1 ^ sw)] = o1;
                }
            }
            __syncthreads();
            #pragma unroll
            for (int it = 0; it < 8; ++it) {
                int idx = it * 256 + t;
                int r = idx >> 5, q4 = (idx & 31) * 4;  // r: 0..63, q4: word in row
                int row = half * 64 + r;
                if (row < vrows) {
                    int sw = ((row >> 2) & 3) << 4;
                    float4 v4 = *(const float4*)&Alf[r * 128 + (q4 ^ sw)];
                    *(float4*)(out + (size_t)eI[row] * D + q4) = v4;
                }
            }
            __syncthreads();
        }
    }
}

extern "C" void kernel_launch(void* const* d_in, const int* in_sizes, int n_in,
                              void* d_out, int out_size, void* d_ws, size_t ws_size,
                              hipStream_t stream)
{
    const float* values    = (const float*)d_in[0];
    const int*   view_idx  = (const int*)d_in[1];
    const int*   point_idx = (const int*)d_in[2];
    const float* W_sp   = (const float*)d_in[5];
    const float* b_sp   = (const float*)d_in[6];
    const float* W_view = (const float*)d_in[7];
    const float* b_view = (const float*)d_in[8];
    const float* W_glob = (const float*)d_in[9];
    const float* b_glob = (const float*)d_in[10];
    const float* W_proj = (const float*)d_in[11];
    const float* b_proj = (const float*)d_in[12];
    int nnz = in_sizes[1];
    int ntiles = (nnz + 127) / 128;

    // ws: [gs|Cp|Cv](memset) | bsum|bbase|Bp|Bv | plv|vlist|psp | Wt4 | mbuf | fbp | vbuf16
    char* w = (char*)d_ws;
    float* gs = (float*)w;                          w += 128 * 4;
    int* Cp   = (int*)w;                            w += (size_t)NP * 4;
    int* Cv   = (int*)w;                            w += (size_t)NV * 4;
    size_t zero_bytes = (size_t)(w - (char*)d_ws);
    int* bsum = (int*)w;                            w += 64 * 4;
    int* bbase = (int*)w;                           w += 64 * 4;
    int* Bp   = (int*)w;                            w += (size_t)NP * 4;
    int* Bv   = (int*)w;                            w += (size_t)NV * 4;
    uint2* plv = (uint2*)w;                         w += (size_t)nnz * 8;
    int* vlist = (int*)w;                           w += (size_t)nnz * 4;
    int* psp  = (int*)w;                            w += (size_t)nnz * 4;
    unsigned short* Wt4 = (unsigned short*)w;       w += (size_t)4 * 16384 * 2;
    unsigned int* mbuf = (unsigned int*)w;          w += (size_t)(NP + NV) * 64 * 4;
    unsigned int* fbp = (unsigned int*)w;           w += (size_t)(NP + NV + 1) * 64 * 4;
    unsigned int* vbuf16 = (unsigned int*)w;        w += (size_t)ntiles * 128 * 64 * 4;

    hipMemsetAsync(d_ws, 0, zero_bytes, stream);

    hipLaunchKernelGGL(k_prep, dim3(4), dim3(256), 0, stream,
                       W_sp, W_view, W_glob, W_proj, Wt4);
    hipLaunchKernelGGL(k_count, dim3(1024), dim3(256), 0, stream,
                       view_idx, point_idx, Cp, Cv, nnz);
    hipLaunchKernelGGL(k_scanA, dim3(64), dim3(256), 0, stream, Cp, bsum);
    hipLaunchKernelGGL(k_scanB, dim3(1), dim3(256), 0, stream, bsum, bbase, Cv, Bv);
    hipLaunchKernelGGL(k_scanC, dim3(64), dim3(256), 0, stream, Cp, Bp, bbase);
    hipLaunchKernelGGL(k_scatter_cvt, dim3(2048), dim3(256), 0, stream,
                       values, view_idx, point_idx, Cp, Cv, plv, vlist, vbuf16, nnz);
    hipLaunchKernelGGL(k_psum, dim3(2048), dim3(256), 0, stream,
                       vbuf16, Bp, Cp, mbuf, psp);
    hipLaunchKernelGGL(k_vsum, dim3(NV), dim3(256), 0, stream,
                       vbuf16, vlist, Bv, Cv, mbuf, gs);
    hipLaunchKernelGGL(k_featgemm, dim3(521), dim3(256), 0, stream,
                       mbuf, Wt4, b_sp, b_view, b_glob, gs, 1.f / (float)nnz, fbp);
    hipLaunchKernelGGL(k_proj, dim3(2048), dim3(256), 0, stream,
                       vbuf16, plv, psp, Wt4 + (size_t)3 * 16384, b_proj, fbp,
                       (float*)d_out, nnz, ntiles);
}

// Round 8
// 1060.322 us; speedup vs baseline: 1.1581x; 1.1581x over previous
//
#include <hip/hip_runtime.h>

#define D 128
#define NP 65536
#define NV 1024

typedef __attribute__((ext_vector_type(8))) short short8;
typedef __attribute__((ext_vector_type(4))) float f32x4;

__device__ __forceinline__ unsigned short f2bf(float x) {
    unsigned int u = __builtin_bit_cast(unsigned int, x);
    u += 0x7FFFu + ((u >> 16) & 1u);          // round-to-nearest-even
    return (unsigned short)(u >> 16);
}
__device__ __forceinline__ unsigned int pack2bf(float a, float b) {
    return (unsigned int)f2bf(a) | ((unsigned int)f2bf(b) << 16);
}
__device__ __forceinline__ float bflo(unsigned int u) {
    return __builtin_bit_cast(float, u << 16);
}
__device__ __forceinline__ float bfhi(unsigned int u) {
    return __builtin_bit_cast(float, u & 0xFFFF0000u);
}

// ---------------- weight prep: W[k][n] f32 -> Wt[n][k] bf16 ----------------
__global__ __launch_bounds__(256)
void k_prep(const float* __restrict__ Wsp, const float* __restrict__ Wvw,
            const float* __restrict__ Wgl, const float* __restrict__ Wpr,
            unsigned short* __restrict__ o)
{
    const float* W = (blockIdx.x == 0) ? Wsp : (blockIdx.x == 1) ? Wvw
                   : (blockIdx.x == 2) ? Wgl : Wpr;
    unsigned short* Wt = o + (size_t)blockIdx.x * 16384;
    for (int c = threadIdx.x; c < 2048; c += 256) {
        int n = c >> 4, kb = (c & 15) * 8;
        unsigned int p[4];
        #pragma unroll
        for (int j = 0; j < 4; ++j)
            p[j] = pack2bf(W[(kb + 2 * j) * D + n], W[(kb + 2 * j + 1) * D + n]);
        *(short8*)(Wt + n * 128 + kb) = *(short8*)p;
    }
}

// ---------------- CSR build ----------------
__global__ __launch_bounds__(256)
void k_count(const int* __restrict__ vi, const int* __restrict__ pi,
             int* __restrict__ cp, int* __restrict__ cv, int nnz)
{
    int i = blockIdx.x * blockDim.x + threadIdx.x;
    int n = gridDim.x * blockDim.x;
    for (int e = i; e < nnz; e += n) {
        atomicAdd(&cp[pi[e]], 1);
        atomicAdd(&cv[vi[e]], 1);
    }
}

__global__ __launch_bounds__(256)
void k_scanA(const int* __restrict__ cp, int* __restrict__ bsum)
{
    __shared__ int l[256];
    int t = threadIdx.x;
    int4 c = ((const int4*)cp)[blockIdx.x * 256 + t];
    l[t] = c.x + c.y + c.z + c.w;
    __syncthreads();
    for (int d = 128; d > 0; d >>= 1) {
        if (t < d) l[t] += l[t + d];
        __syncthreads();
    }
    if (t == 0) bsum[blockIdx.x] = l[0];
}

__global__ __launch_bounds__(256)
void k_scanB(const int* __restrict__ bsum, int* __restrict__ bbase,
             int* __restrict__ cv, int* __restrict__ bv)
{
    __shared__ int l[256];
    int t = threadIdx.x;
    int own = (t < 64) ? bsum[t] : 0;
    l[t] = own;
    __syncthreads();
    for (int d = 1; d < 64; d <<= 1) {
        int u = (t >= d && t < 64) ? l[t - d] : 0;
        __syncthreads();
        if (t < 64) l[t] += u;
        __syncthreads();
    }
    if (t < 64) bbase[t] = l[t] - own;
    __syncthreads();
    int4 c = ((const int4*)cv)[t];
    int s4 = c.x + c.y + c.z + c.w;
    l[t] = s4;
    __syncthreads();
    for (int d = 1; d < 256; d <<= 1) {
        int u = (t >= d) ? l[t - d] : 0;
        __syncthreads();
        l[t] += u;
        __syncthreads();
    }
    int ex = l[t] - s4;
    int4 o; o.x = ex; o.y = ex + c.x; o.z = o.y + c.y; o.w = o.z + c.z;
    ((int4*)bv)[t] = o;
    ((int4*)cv)[t] = o;
}

__global__ __launch_bounds__(256)
void k_scanC(int* __restrict__ cp, int* __restrict__ bp, const int* __restrict__ bbase)
{
    __shared__ int l[256];
    int t = threadIdx.x;
    int i = blockIdx.x * 256 + t;
    int4 c = ((const int4*)cp)[i];
    int s4 = c.x + c.y + c.z + c.w;
    l[t] = s4;
    __syncthreads();
    for (int d = 1; d < 256; d <<= 1) {
        int u = (t >= d) ? l[t - d] : 0;
        __syncthreads();
        l[t] += u;
        __syncthreads();
    }
    int ex = l[t] - s4 + bbase[blockIdx.x];
    int4 o; o.x = ex; o.y = ex + c.x; o.z = o.y + c.y; o.w = o.z + c.z;
    ((int4*)bp)[i] = o;
    ((int4*)cp)[i] = o;
}

// ---------------- scatter + bf16 convert (sequential values read) ----------------
// vlist[sv] = sp (plist position); vbuf16[sp] = bf16 row of entry.
__global__ __launch_bounds__(256)
void k_scatter_cvt(const float* __restrict__ values, const int* __restrict__ vi,
                   const int* __restrict__ pi, int* __restrict__ curp,
                   int* __restrict__ curv, int* __restrict__ vlist,
                   unsigned int* __restrict__ vbuf16, int nnz)
{
    int lane = threadIdx.x & 63, wv = threadIdx.x >> 6;
    int wave = blockIdx.x * 4 + wv, nw = gridDim.x * 4;
    for (int base = wave * 64; base < nnz; base += nw * 64) {
        int e = base + lane;
        int sp = 0;
        if (e < nnz) {
            int p = pi[e], v = vi[e];
            sp = atomicAdd(&curp[p], 1);
            int sv = atomicAdd(&curv[v], 1);
            vlist[sv] = sp;
        }
        int n = min(64, nnz - base);
        int j = 0;
        for (; j + 4 <= n; j += 4) {
            int s0 = __builtin_amdgcn_readlane(sp, j);
            int s1 = __builtin_amdgcn_readlane(sp, j + 1);
            int s2 = __builtin_amdgcn_readlane(sp, j + 2);
            int s3 = __builtin_amdgcn_readlane(sp, j + 3);
            float2 a = *(const float2*)(values + (size_t)(base + j) * D + lane * 2);
            float2 b = *(const float2*)(values + (size_t)(base + j + 1) * D + lane * 2);
            float2 c = *(const float2*)(values + (size_t)(base + j + 2) * D + lane * 2);
            float2 d = *(const float2*)(values + (size_t)(base + j + 3) * D + lane * 2);
            vbuf16[(size_t)s0 * 64 + lane] = pack2bf(a.x, a.y);
            vbuf16[(size_t)s1 * 64 + lane] = pack2bf(b.x, b.y);
            vbuf16[(size_t)s2 * 64 + lane] = pack2bf(c.x, c.y);
            vbuf16[(size_t)s3 * 64 + lane] = pack2bf(d.x, d.y);
        }
        for (; j < n; ++j) {
            int s0 = __builtin_amdgcn_readlane(sp, j);
            float2 a = *(const float2*)(values + (size_t)(base + j) * D + lane * 2);
            vbuf16[(size_t)s0 * 64 + lane] = pack2bf(a.x, a.y);
        }
    }
}

// ---------------- point sums: fully sequential over vbuf16 ----------------
__global__ __launch_bounds__(256)
void k_psum(const unsigned int* __restrict__ vbuf16, const int* __restrict__ pbase,
            const int* __restrict__ pend, unsigned int* __restrict__ mbuf)
{
    int lane = threadIdx.x & 63, wv = threadIdx.x >> 6;
    int wave = blockIdx.x * 4 + wv, nw = gridDim.x * 4;
    for (int pt = wave; pt < NP; pt += nw) {
        int s = pbase[pt], e = pend[pt];
        float s0 = 0.f, s1 = 0.f;
        int i = s;
        for (; i + 4 <= e; i += 4) {
            unsigned int u0 = vbuf16[(size_t)i * 64 + lane];
            unsigned int u1 = vbuf16[(size_t)(i + 1) * 64 + lane];
            unsigned int u2 = vbuf16[(size_t)(i + 2) * 64 + lane];
            unsigned int u3 = vbuf16[(size_t)(i + 3) * 64 + lane];
            s0 += bflo(u0) + bflo(u1) + bflo(u2) + bflo(u3);
            s1 += bfhi(u0) + bfhi(u1) + bfhi(u2) + bfhi(u3);
        }
        for (; i < e; ++i) {
            unsigned int u = vbuf16[(size_t)i * 64 + lane];
            s0 += bflo(u); s1 += bfhi(u);
        }
        float inv = 1.f / fmaxf((float)(e - s), 1.f);
        mbuf[(size_t)pt * 64 + lane] = pack2bf(s0 * inv, s1 * inv);
    }
}

// ---------------- view sums from bf16 rows (8 rows in flight) ----------------
__global__ __launch_bounds__(256)
void k_vsum(const unsigned int* __restrict__ vbuf16, const int* __restrict__ vlist,
            const int* __restrict__ vbase, const int* __restrict__ vend,
            unsigned int* __restrict__ mbuf, float* __restrict__ gs)
{
    __shared__ float2 red[4][64];
    int lane = threadIdx.x & 63, wv = threadIdx.x >> 6;
    int v = blockIdx.x;
    int s = vbase[v], e = vend[v];
    float s0 = 0.f, s1 = 0.f;
    for (int b = s + wv * 64; b < e; b += 256) {
        int n = min(64, e - b);
        int idx = (lane < n) ? vlist[b + lane] : 0;
        int j = 0;
        for (; j + 8 <= n; j += 8) {
            unsigned int u[8];
            #pragma unroll
            for (int q = 0; q < 8; ++q) {
                int r = __builtin_amdgcn_readlane(idx, j + q);
                u[q] = vbuf16[(size_t)r * 64 + lane];
            }
            #pragma unroll
            for (int q = 0; q < 8; ++q) { s0 += bflo(u[q]); s1 += bfhi(u[q]); }
        }
        for (; j < n; ++j) {
            int r = __builtin_amdgcn_readlane(idx, j);
            unsigned int u = vbuf16[(size_t)r * 64 + lane];
            s0 += bflo(u); s1 += bfhi(u);
        }
    }
    red[wv][lane] = make_float2(s0, s1);
    __syncthreads();
    if (wv == 0) {
        float2 a = red[0][lane], b2 = red[1][lane], c = red[2][lane], d2 = red[3][lane];
        float t0 = a.x + b2.x + c.x + d2.x;
        float t1 = a.y + b2.y + c.y + d2.y;
        atomicAdd(&gs[lane * 2], t0);
        atomicAdd(&gs[lane * 2 + 1], t1);
        float inv = 1.f / fmaxf((float)(e - s), 1.f);
        mbuf[(size_t)(NP + v) * 64 + lane] = pack2bf(t0 * inv, t1 * inv);
    }
}

// ---------------- shared MFMA tile machinery ----------------
// LDS layout: bf16 [128 rows][128 k], byte addr = (row*256 + k*2) ^ ((row&7)<<4)

__device__ __forceinline__ void stage_bf16(const unsigned short* __restrict__ g,
                                           unsigned short* lds, int t)
{
    #pragma unroll
    for (int i = 0; i < 8; ++i) {
        int c = i * 256 + t;
        int row = c >> 4, kb = (c & 15) * 16;
        short8 v = *(const short8*)(g + row * 128 + (c & 15) * 8);
        *(short8*)&lds[((row * 256 + kb) ^ ((row & 7) << 4)) >> 1] = v;
    }
}

__device__ __forceinline__ void stage_f32_cvt(const float* __restrict__ g, int validrows,
                                              unsigned short* lds, int t)
{
    #pragma unroll 4
    for (int i = 0; i < 8; ++i) {
        int c = i * 256 + t;
        int row = c >> 4, cb = (c & 15) * 8;
        unsigned int p[4] = {0u, 0u, 0u, 0u};
        if (row < validrows) {
            const float4* src = (const float4*)(g + (size_t)row * D + cb);
            float4 u = src[0], v = src[1];
            p[0] = pack2bf(u.x, u.y); p[1] = pack2bf(u.z, u.w);
            p[2] = pack2bf(v.x, v.y); p[3] = pack2bf(v.z, v.w);
        }
        *(short8*)&lds[((row * 256 + cb * 2) ^ ((row & 7) << 4)) >> 1] = *(short8*)p;
    }
}

__device__ __forceinline__ void mfma_tile(const unsigned short* Al, const unsigned short* Bl,
                                          int lane, int w, f32x4 acc[8][2])
{
    int lr = lane & 15, lg = lane >> 4;
    #pragma unroll
    for (int kc = 0; kc < 4; ++kc) {
        int kb = kc * 64 + lg * 16;
        int bn0 = w * 32 + lr, bn1 = bn0 + 16;
        short8 b0 = *(const short8*)&Bl[((bn0 * 256 + kb) ^ ((bn0 & 7) << 4)) >> 1];
        short8 b1 = *(const short8*)&Bl[((bn1 * 256 + kb) ^ ((bn1 & 7) << 4)) >> 1];
        #pragma unroll
        for (int m = 0; m < 8; ++m) {
            int row = m * 16 + lr;
            short8 a = *(const short8*)&Al[((row * 256 + kb) ^ ((row & 7) << 4)) >> 1];
            acc[m][0] = __builtin_amdgcn_mfma_f32_16x16x32_bf16(a, b0, acc[m][0], 0, 0, 0);
            acc[m][1] = __builtin_amdgcn_mfma_f32_16x16x32_bf16(a, b1, acc[m][1], 0, 0, 0);
        }
    }
}

// ---------------- feature GEMM -> packed (c,c+16) uint rows ----------------
__global__ __launch_bounds__(256)
void k_featgemm(const unsigned int* __restrict__ mbuf, const unsigned short* __restrict__ Wt4,
                const float* __restrict__ bSp, const float* __restrict__ bVw,
                const float* __restrict__ bGl, const float* __restrict__ gs,
                float inv_nnz, unsigned int* __restrict__ fbp)
{
    __shared__ unsigned short Al[128 * 128];
    __shared__ unsigned short Bl[128 * 128];
    int t = threadIdx.x;
    int tile = blockIdx.x;   // 0..520
    const unsigned short* Wt; const float* bias; int rowbase; int vrows = 128;
    if (tile < 512)      { Wt = Wt4;             bias = bSp; rowbase = tile * 128; }
    else if (tile < 520) { Wt = Wt4 + 16384;     bias = bVw; rowbase = NP + (tile - 512) * 128; }
    else                 { Wt = Wt4 + 2 * 16384; bias = bGl; rowbase = NP + NV; vrows = 1; }
    stage_bf16(Wt, Bl, t);
    if (tile < 520) {
        stage_bf16((const unsigned short*)(mbuf + (size_t)rowbase * 64), Al, t);
    } else {
        #pragma unroll
        for (int i = 0; i < 8; ++i) {
            int c = i * 256 + t;
            int row = c >> 4, cb = (c & 15) * 8;
            unsigned int p[4] = {0u, 0u, 0u, 0u};
            if (row == 0) {
                #pragma unroll
                for (int j = 0; j < 4; ++j)
                    p[j] = pack2bf(gs[cb + 2 * j] * inv_nnz, gs[cb + 2 * j + 1] * inv_nnz);
            }
            *(short8*)&Al[((row * 256 + cb * 2) ^ ((row & 7) << 4)) >> 1] = *(short8*)p;
        }
    }
    __syncthreads();
    f32x4 acc[8][2] = {};
    int lane = t & 63, w = t >> 6;
    mfma_tile(Al, Bl, lane, w, acc);
    int lr = lane & 15, lg = lane >> 4;
    int c0 = w * 32 + lr, c1 = c0 + 16;
    float bb0 = 0.25f * bias[c0], bb1 = 0.25f * bias[c1];
    #pragma unroll
    for (int m = 0; m < 8; ++m)
        #pragma unroll
        for (int r = 0; r < 4; ++r) {
            int row = m * 16 + lg * 4 + r;
            if (row < vrows)
                fbp[(size_t)(rowbase + row) * 64 + w * 16 + lr] =
                    pack2bf(acc[m][0][r] * 0.25f + bb0, acc[m][1][r] * 0.25f + bb1);
        }
}

// ---------------- projection in ENTRY order: sequential A and out ----------------
__global__ __launch_bounds__(256, 4)
void k_proj(const float* __restrict__ values, const int* __restrict__ point_idx,
            const int* __restrict__ view_idx, const unsigned short* __restrict__ WtPr,
            const float* __restrict__ bPr, const unsigned int* __restrict__ fbp,
            float* __restrict__ out, int nnz, int ntiles)
{
    __shared__ unsigned short Al[128 * 128];   // 32 KB
    __shared__ int pI[128], vI[128];
    int t = threadIdx.x, lane = t & 63, w = t >> 6;
    int lr = lane & 15, lg = lane >> 4;
    short8 Bf[4][2];
    #pragma unroll
    for (int kc = 0; kc < 4; ++kc) {
        Bf[kc][0] = *(const short8*)(WtPr + (w * 32 + lr) * 128 + kc * 32 + lg * 8);
        Bf[kc][1] = *(const short8*)(WtPr + (w * 32 + lr + 16) * 128 + kc * 32 + lg * 8);
    }
    int c0 = w * 32 + lr, c1 = c0 + 16;
    unsigned int gw = fbp[(size_t)(NP + NV) * 64 + w * 16 + lr];
    float base0 = 0.25f * bPr[c0] + bflo(gw);
    float base1 = 0.25f * bPr[c1] + bfhi(gw);
    const unsigned int* pfp = fbp;
    const unsigned int* vfp = fbp + (size_t)NP * 64;
    for (int tile = blockIdx.x; tile < ntiles; tile += gridDim.x) {
        int e0 = tile * 128;
        int vrows = min(128, nnz - e0);
        stage_f32_cvt(values + (size_t)e0 * D, vrows, Al, t);
        if (t < 128) pI[t] = (t < vrows) ? point_idx[e0 + t] : 0;
        else { int u = t - 128; vI[u] = (u < vrows) ? view_idx[e0 + u] : 0; }
        __syncthreads();
        f32x4 acc[8][2] = {};
        #pragma unroll
        for (int kc = 0; kc < 4; ++kc) {
            int kb = kc * 64 + lg * 16;
            #pragma unroll
            for (int m = 0; m < 8; ++m) {
                int row = m * 16 + lr;
                short8 a = *(const short8*)&Al[((row * 256 + kb) ^ ((row & 7) << 4)) >> 1];
                acc[m][0] = __builtin_amdgcn_mfma_f32_16x16x32_bf16(a, Bf[kc][0], acc[m][0], 0, 0, 0);
                acc[m][1] = __builtin_amdgcn_mfma_f32_16x16x32_bf16(a, Bf[kc][1], acc[m][1], 0, 0, 0);
            }
        }
        #pragma unroll
        for (int m = 0; m < 8; ++m)
            #pragma unroll
            for (int r = 0; r < 4; ++r) {
                int row = m * 16 + lg * 4 + r;
                if (row < vrows) {
                    int p = pI[row], vv = vI[row];
                    unsigned int pu = pfp[(size_t)p * 64 + w * 16 + lr];
                    unsigned int vu = vfp[(size_t)vv * 64 + w * 16 + lr];
                    size_t o = (size_t)(e0 + row) * D;
                    out[o + c0] = acc[m][0][r] * 0.25f + base0 + bflo(pu) + bflo(vu);
                    out[o + c1] = acc[m][1][r] * 0.25f + base1 + bfhi(pu) + bfhi(vu);
                }
            }
        __syncthreads();   // protect Al/pI/vI before next tile
    }
}

extern "C" void kernel_launch(void* const* d_in, const int* in_sizes, int n_in,
                              void* d_out, int out_size, void* d_ws, size_t ws_size,
                              hipStream_t stream)
{
    const float* values    = (const float*)d_in[0];
    const int*   view_idx  = (const int*)d_in[1];
    const int*   point_idx = (const int*)d_in[2];
    const float* W_sp   = (const float*)d_in[5];
    const float* b_sp   = (const float*)d_in[6];
    const float* W_view = (const float*)d_in[7];
    const float* b_view = (const float*)d_in[8];
    const float* W_glob = (const float*)d_in[9];
    const float* b_glob = (const float*)d_in[10];
    const float* W_proj = (const float*)d_in[11];
    const float* b_proj = (const float*)d_in[12];
    int nnz = in_sizes[1];
    int ntiles = (nnz + 127) / 128;

    // ws: [gs|Cp|Cv](memset) | bsum|bbase|Bp|Bv | vlist | Wt4 | mbuf | fbp | vbuf16
    char* w = (char*)d_ws;
    float* gs = (float*)w;                          w += 128 * 4;
    int* Cp   = (int*)w;                            w += (size_t)NP * 4;
    int* Cv   = (int*)w;                            w += (size_t)NV * 4;
    size_t zero_bytes = (size_t)(w - (char*)d_ws);
    int* bsum = (int*)w;                            w += 64 * 4;
    int* bbase = (int*)w;                           w += 64 * 4;
    int* Bp   = (int*)w;                            w += (size_t)NP * 4;
    int* Bv   = (int*)w;                            w += (size_t)NV * 4;
    int* vlist = (int*)w;                           w += (size_t)nnz * 4;
    unsigned short* Wt4 = (unsigned short*)w;       w += (size_t)4 * 16384 * 2;
    unsigned int* mbuf = (unsigned int*)w;          w += (size_t)(NP + NV) * 64 * 4;
    unsigned int* fbp = (unsigned int*)w;           w += (size_t)(NP + NV + 1) * 64 * 4;
    unsigned int* vbuf16 = (unsigned int*)w;        w += (size_t)ntiles * 128 * 64 * 4;

    hipMemsetAsync(d_ws, 0, zero_bytes, stream);

    hipLaunchKernelGGL(k_prep, dim3(4), dim3(256), 0, stream,
                       W_sp, W_view, W_glob, W_proj, Wt4);
    hipLaunchKernelGGL(k_count, dim3(1024), dim3(256), 0, stream,
                       view_idx, point_idx, Cp, Cv, nnz);
    hipLaunchKernelGGL(k_scanA, dim3(64), dim3(256), 0, stream, Cp, bsum);
    hipLaunchKernelGGL(k_scanB, dim3(1), dim3(256), 0, stream, bsum, bbase, Cv, Bv);
    hipLaunchKernelGGL(k_scanC, dim3(64), dim3(256), 0, stream, Cp, Bp, bbase);
    hipLaunchKernelGGL(k_scatter_cvt, dim3(2048), dim3(256), 0, stream,
                       values, view_idx, point_idx, Cp, Cv, vlist, vbuf16, nnz);
    hipLaunchKernelGGL(k_psum, dim3(2048), dim3(256), 0, stream,
                       vbuf16, Bp, Cp, mbuf);
    hipLaunchKernelGGL(k_vsum, dim3(NV), dim3(256), 0, stream,
                       vbuf16, vlist, Bv, Cv, mbuf, gs);
    hipLaunchKernelGGL(k_featgemm, dim3(521), dim3(256), 0, stream,
                       mbuf, Wt4, b_sp, b_view, b_glob, gs, 1.f / (float)nnz, fbp);
    hipLaunchKernelGGL(k_proj, dim3(2048), dim3(256), 0, stream,
                       values, point_idx, view_idx, Wt4 + (size_t)3 * 16384, b_proj, fbp,
                       (float*)d_out, nnz, ntiles);
}

// Round 9
// 1045.303 us; speedup vs baseline: 1.1747x; 1.0144x over previous
//
#include <hip/hip_runtime.h>

#define D 128
#define NP 65536
#define NV 1024

typedef __attribute__((ext_vector_type(8))) short short8;
typedef __attribute__((ext_vector_type(4))) float f32x4;

__device__ __forceinline__ unsigned short f2bf(float x) {
    unsigned int u = __builtin_bit_cast(unsigned int, x);
    u += 0x7FFFu + ((u >> 16) & 1u);          // round-to-nearest-even
    return (unsigned short)(u >> 16);
}
__device__ __forceinline__ unsigned int pack2bf(float a, float b) {
    return (unsigned int)f2bf(a) | ((unsigned int)f2bf(b) << 16);
}
__device__ __forceinline__ float bflo(unsigned int u) {
    return __builtin_bit_cast(float, u << 16);
}
__device__ __forceinline__ float bfhi(unsigned int u) {
    return __builtin_bit_cast(float, u & 0xFFFF0000u);
}
__device__ __forceinline__ f32x4 ntld4(const float* p) {
    return __builtin_nontemporal_load((const f32x4*)p);
}
__device__ __forceinline__ void ntst(float* p, float v) {
    __builtin_nontemporal_store(v, p);
}

// ---------------- weight prep: W[k][n] f32 -> Wt[n][k] bf16 ----------------
__global__ __launch_bounds__(256)
void k_prep(const float* __restrict__ Wsp, const float* __restrict__ Wvw,
            const float* __restrict__ Wgl, const float* __restrict__ Wpr,
            unsigned short* __restrict__ o)
{
    const float* W = (blockIdx.x == 0) ? Wsp : (blockIdx.x == 1) ? Wvw
                   : (blockIdx.x == 2) ? Wgl : Wpr;
    unsigned short* Wt = o + (size_t)blockIdx.x * 16384;
    for (int c = threadIdx.x; c < 2048; c += 256) {
        int n = c >> 4, kb = (c & 15) * 8;
        unsigned int p[4];
        #pragma unroll
        for (int j = 0; j < 4; ++j)
            p[j] = pack2bf(W[(kb + 2 * j) * D + n], W[(kb + 2 * j + 1) * D + n]);
        *(short8*)(Wt + n * 128 + kb) = *(short8*)p;
    }
}

// ---------------- CSR build ----------------
__global__ __launch_bounds__(256)
void k_count(const int* __restrict__ vi, const int* __restrict__ pi,
             int* __restrict__ cp, int* __restrict__ cv, int nnz)
{
    int i = blockIdx.x * blockDim.x + threadIdx.x;
    int n = gridDim.x * blockDim.x;
    for (int e = i; e < nnz; e += n) {
        atomicAdd(&cp[pi[e]], 1);
        atomicAdd(&cv[vi[e]], 1);
    }
}

__global__ __launch_bounds__(256)
void k_scanA(const int* __restrict__ cp, int* __restrict__ bsum)
{
    __shared__ int l[256];
    int t = threadIdx.x;
    int4 c = ((const int4*)cp)[blockIdx.x * 256 + t];
    l[t] = c.x + c.y + c.z + c.w;
    __syncthreads();
    for (int d = 128; d > 0; d >>= 1) {
        if (t < d) l[t] += l[t + d];
        __syncthreads();
    }
    if (t == 0) bsum[blockIdx.x] = l[0];
}

__global__ __launch_bounds__(256)
void k_scanB(const int* __restrict__ bsum, int* __restrict__ bbase,
             int* __restrict__ cv, int* __restrict__ bv)
{
    __shared__ int l[256];
    int t = threadIdx.x;
    int own = (t < 64) ? bsum[t] : 0;
    l[t] = own;
    __syncthreads();
    for (int d = 1; d < 64; d <<= 1) {
        int u = (t >= d && t < 64) ? l[t - d] : 0;
        __syncthreads();
        if (t < 64) l[t] += u;
        __syncthreads();
    }
    if (t < 64) bbase[t] = l[t] - own;
    __syncthreads();
    int4 c = ((const int4*)cv)[t];
    int s4 = c.x + c.y + c.z + c.w;
    l[t] = s4;
    __syncthreads();
    for (int d = 1; d < 256; d <<= 1) {
        int u = (t >= d) ? l[t - d] : 0;
        __syncthreads();
        l[t] += u;
        __syncthreads();
    }
    int ex = l[t] - s4;
    int4 o; o.x = ex; o.y = ex + c.x; o.z = o.y + c.y; o.w = o.z + c.z;
    ((int4*)bv)[t] = o;
    ((int4*)cv)[t] = o;
}

__global__ __launch_bounds__(256)
void k_scanC(int* __restrict__ cp, int* __restrict__ bp, const int* __restrict__ bbase)
{
    __shared__ int l[256];
    int t = threadIdx.x;
    int i = blockIdx.x * 256 + t;
    int4 c = ((const int4*)cp)[i];
    int s4 = c.x + c.y + c.z + c.w;
    l[t] = s4;
    __syncthreads();
    for (int d = 1; d < 256; d <<= 1) {
        int u = (t >= d) ? l[t - d] : 0;
        __syncthreads();
        l[t] += u;
        __syncthreads();
    }
    int ex = l[t] - s4 + bbase[blockIdx.x];
    int4 o; o.x = ex; o.y = ex + c.x; o.z = o.y + c.y; o.w = o.z + c.z;
    ((int4*)bp)[i] = o;
    ((int4*)cp)[i] = o;
}

// ---------------- scatter + bf16 convert (sequential values read, nt) ----------------
__global__ __launch_bounds__(256)
void k_scatter_cvt(const float* __restrict__ values, const int* __restrict__ vi,
                   const int* __restrict__ pi, int* __restrict__ curp,
                   int* __restrict__ curv, int* __restrict__ vlist,
                   unsigned int* __restrict__ vbuf16, int nnz)
{
    int lane = threadIdx.x & 63, wv = threadIdx.x >> 6;
    int wave = blockIdx.x * 4 + wv, nw = gridDim.x * 4;
    for (int base = wave * 64; base < nnz; base += nw * 64) {
        int e = base + lane;
        int sp = 0;
        if (e < nnz) {
            int p = pi[e], v = vi[e];
            sp = atomicAdd(&curp[p], 1);
            int sv = atomicAdd(&curv[v], 1);
            vlist[sv] = sp;
        }
        int n = min(64, nnz - base);
        int j = 0;
        for (; j + 4 <= n; j += 4) {
            int s0 = __builtin_amdgcn_readlane(sp, j);
            int s1 = __builtin_amdgcn_readlane(sp, j + 1);
            int s2 = __builtin_amdgcn_readlane(sp, j + 2);
            int s3 = __builtin_amdgcn_readlane(sp, j + 3);
            f32x4 a, b, c, d;
            {
                const float* q0 = values + (size_t)(base + j) * D + lane * 2;
                // two lanes' dims packed as float2 -> use 8B loads via f32x4 on even lanes? keep float2
                float2 a2 = *(const float2*)q0;
                float2 b2 = *(const float2*)(q0 + D);
                float2 c2 = *(const float2*)(q0 + 2 * D);
                float2 d2 = *(const float2*)(q0 + 3 * D);
                a[0] = a2.x; a[1] = a2.y; b[0] = b2.x; b[1] = b2.y;
                c[0] = c2.x; c[1] = c2.y; d[0] = d2.x; d[1] = d2.y;
            }
            vbuf16[(size_t)s0 * 64 + lane] = pack2bf(a[0], a[1]);
            vbuf16[(size_t)s1 * 64 + lane] = pack2bf(b[0], b[1]);
            vbuf16[(size_t)s2 * 64 + lane] = pack2bf(c[0], c[1]);
            vbuf16[(size_t)s3 * 64 + lane] = pack2bf(d[0], d[1]);
        }
        for (; j < n; ++j) {
            int s0 = __builtin_amdgcn_readlane(sp, j);
            float2 a = *(const float2*)(values + (size_t)(base + j) * D + lane * 2);
            vbuf16[(size_t)s0 * 64 + lane] = pack2bf(a.x, a.y);
        }
    }
}

// ---------------- point sums: fully sequential over vbuf16 ----------------
__global__ __launch_bounds__(256)
void k_psum(const unsigned int* __restrict__ vbuf16, const int* __restrict__ pbase,
            const int* __restrict__ pend, unsigned int* __restrict__ mbuf)
{
    int lane = threadIdx.x & 63, wv = threadIdx.x >> 6;
    int wave = blockIdx.x * 4 + wv, nw = gridDim.x * 4;
    for (int pt = wave; pt < NP; pt += nw) {
        int s = pbase[pt], e = pend[pt];
        float s0 = 0.f, s1 = 0.f;
        int i = s;
        for (; i + 4 <= e; i += 4) {
            unsigned int u0 = vbuf16[(size_t)i * 64 + lane];
            unsigned int u1 = vbuf16[(size_t)(i + 1) * 64 + lane];
            unsigned int u2 = vbuf16[(size_t)(i + 2) * 64 + lane];
            unsigned int u3 = vbuf16[(size_t)(i + 3) * 64 + lane];
            s0 += bflo(u0) + bflo(u1) + bflo(u2) + bflo(u3);
            s1 += bfhi(u0) + bfhi(u1) + bfhi(u2) + bfhi(u3);
        }
        for (; i < e; ++i) {
            unsigned int u = vbuf16[(size_t)i * 64 + lane];
            s0 += bflo(u); s1 += bfhi(u);
        }
        float inv = 1.f / fmaxf((float)(e - s), 1.f);
        mbuf[(size_t)pt * 64 + lane] = pack2bf(s0 * inv, s1 * inv);
    }
}

// ---------------- view sums: 8 waves/block, 8 rows in flight ----------------
__global__ __launch_bounds__(512)
void k_vsum(const unsigned int* __restrict__ vbuf16, const int* __restrict__ vlist,
            const int* __restrict__ vbase, const int* __restrict__ vend,
            unsigned int* __restrict__ mbuf, float* __restrict__ gs)
{
    __shared__ float2 red[8][64];
    int lane = threadIdx.x & 63, wv = threadIdx.x >> 6;
    int v = blockIdx.x;
    int s = vbase[v], e = vend[v];
    float s0 = 0.f, s1 = 0.f;
    for (int b = s + wv * 64; b < e; b += 512) {
        int n = min(64, e - b);
        int idx = (lane < n) ? vlist[b + lane] : 0;
        int j = 0;
        for (; j + 8 <= n; j += 8) {
            unsigned int u[8];
            #pragma unroll
            for (int q = 0; q < 8; ++q) {
                int r = __builtin_amdgcn_readlane(idx, j + q);
                u[q] = vbuf16[(size_t)r * 64 + lane];
            }
            #pragma unroll
            for (int q = 0; q < 8; ++q) { s0 += bflo(u[q]); s1 += bfhi(u[q]); }
        }
        for (; j < n; ++j) {
            int r = __builtin_amdgcn_readlane(idx, j);
            unsigned int u = vbuf16[(size_t)r * 64 + lane];
            s0 += bflo(u); s1 += bfhi(u);
        }
    }
    red[wv][lane] = make_float2(s0, s1);
    __syncthreads();
    if (wv == 0) {
        float t0 = 0.f, t1 = 0.f;
        #pragma unroll
        for (int q = 0; q < 8; ++q) { t0 += red[q][lane].x; t1 += red[q][lane].y; }
        atomicAdd(&gs[lane * 2], t0);
        atomicAdd(&gs[lane * 2 + 1], t1);
        float inv = 1.f / fmaxf((float)(e - s), 1.f);
        mbuf[(size_t)(NP + v) * 64 + lane] = pack2bf(t0 * inv, t1 * inv);
    }
}

// ---------------- shared MFMA tile machinery ----------------
// LDS layout: bf16 [128 rows][128 k], byte addr = (row*256 + k*2) ^ ((row&7)<<4)

__device__ __forceinline__ void stage_bf16(const unsigned short* __restrict__ g,
                                           unsigned short* lds, int t)
{
    #pragma unroll
    for (int i = 0; i < 8; ++i) {
        int c = i * 256 + t;
        int row = c >> 4, kb = (c & 15) * 16;
        short8 v = *(const short8*)(g + row * 128 + (c & 15) * 8);
        *(short8*)&lds[((row * 256 + kb) ^ ((row & 7) << 4)) >> 1] = v;
    }
}

__device__ __forceinline__ void stage_f32_cvt_nt(const float* __restrict__ g, int validrows,
                                                 unsigned short* lds, int t)
{
    #pragma unroll 4
    for (int i = 0; i < 8; ++i) {
        int c = i * 256 + t;
        int row = c >> 4, cb = (c & 15) * 8;
        unsigned int p[4] = {0u, 0u, 0u, 0u};
        if (row < validrows) {
            const float* src = g + (size_t)row * D + cb;
            f32x4 u = ntld4(src), v = ntld4(src + 4);
            p[0] = pack2bf(u[0], u[1]); p[1] = pack2bf(u[2], u[3]);
            p[2] = pack2bf(v[0], v[1]); p[3] = pack2bf(v[2], v[3]);
        }
        *(short8*)&lds[((row * 256 + cb * 2) ^ ((row & 7) << 4)) >> 1] = *(short8*)p;
    }
}

__device__ __forceinline__ void mfma_tile(const unsigned short* Al, const unsigned short* Bl,
                                          int lane, int w, f32x4 acc[8][2])
{
    int lr = lane & 15, lg = lane >> 4;
    #pragma unroll
    for (int kc = 0; kc < 4; ++kc) {
        int kb = kc * 64 + lg * 16;
        int bn0 = w * 32 + lr, bn1 = bn0 + 16;
        short8 b0 = *(const short8*)&Bl[((bn0 * 256 + kb) ^ ((bn0 & 7) << 4)) >> 1];
        short8 b1 = *(const short8*)&Bl[((bn1 * 256 + kb) ^ ((bn1 & 7) << 4)) >> 1];
        #pragma unroll
        for (int m = 0; m < 8; ++m) {
            int row = m * 16 + lr;
            short8 a = *(const short8*)&Al[((row * 256 + kb) ^ ((row & 7) << 4)) >> 1];
            acc[m][0] = __builtin_amdgcn_mfma_f32_16x16x32_bf16(a, b0, acc[m][0], 0, 0, 0);
            acc[m][1] = __builtin_amdgcn_mfma_f32_16x16x32_bf16(a, b1, acc[m][1], 0, 0, 0);
        }
    }
}

// ---------------- feature GEMM -> packed (c,c+16) uint rows ----------------
__global__ __launch_bounds__(256)
void k_featgemm(const unsigned int* __restrict__ mbuf, const unsigned short* __restrict__ Wt4,
                const float* __restrict__ bSp, const float* __restrict__ bVw,
                const float* __restrict__ bGl, const float* __restrict__ gs,
                float inv_nnz, unsigned int* __restrict__ fbp)
{
    __shared__ unsigned short Al[128 * 128];
    __shared__ unsigned short Bl[128 * 128];
    int t = threadIdx.x;
    int tile = blockIdx.x;   // 0..520
    const unsigned short* Wt; const float* bias; int rowbase; int vrows = 128;
    if (tile < 512)      { Wt = Wt4;             bias = bSp; rowbase = tile * 128; }
    else if (tile < 520) { Wt = Wt4 + 16384;     bias = bVw; rowbase = NP + (tile - 512) * 128; }
    else                 { Wt = Wt4 + 2 * 16384; bias = bGl; rowbase = NP + NV; vrows = 1; }
    stage_bf16(Wt, Bl, t);
    if (tile < 520) {
        stage_bf16((const unsigned short*)(mbuf + (size_t)rowbase * 64), Al, t);
    } else {
        #pragma unroll
        for (int i = 0; i < 8; ++i) {
            int c = i * 256 + t;
            int row = c >> 4, cb = (c & 15) * 8;
            unsigned int p[4] = {0u, 0u, 0u, 0u};
            if (row == 0) {
                #pragma unroll
                for (int j = 0; j < 4; ++j)
                    p[j] = pack2bf(gs[cb + 2 * j] * inv_nnz, gs[cb + 2 * j + 1] * inv_nnz);
            }
            *(short8*)&Al[((row * 256 + cb * 2) ^ ((row & 7) << 4)) >> 1] = *(short8*)p;
        }
    }
    __syncthreads();
    f32x4 acc[8][2] = {};
    int lane = t & 63, w = t >> 6;
    mfma_tile(Al, Bl, lane, w, acc);
    int lr = lane & 15, lg = lane >> 4;
    int c0 = w * 32 + lr, c1 = c0 + 16;
    float bb0 = 0.25f * bias[c0], bb1 = 0.25f * bias[c1];
    #pragma unroll
    for (int m = 0; m < 8; ++m)
        #pragma unroll
        for (int r = 0; r < 4; ++r) {
            int row = m * 16 + lg * 4 + r;
            if (row < vrows)
                fbp[(size_t)(rowbase + row) * 64 + w * 16 + lr] =
                    pack2bf(acc[m][0][r] * 0.25f + bb0, acc[m][1][r] * 0.25f + bb1);
        }
}

// ---------------- projection in ENTRY order: nt streams, cached feature gathers ----------------
__global__ __launch_bounds__(256, 4)
void k_proj(const float* __restrict__ values, const int* __restrict__ point_idx,
            const int* __restrict__ view_idx, const unsigned short* __restrict__ WtPr,
            const float* __restrict__ bPr, const unsigned int* __restrict__ fbp,
            float* __restrict__ out, int nnz, int ntiles)
{
    __shared__ unsigned short Al[128 * 128];   // 32 KB
    __shared__ int pI[128], vI[128];
    int t = threadIdx.x, lane = t & 63, w = t >> 6;
    int lr = lane & 15, lg = lane >> 4;
    short8 Bf[4][2];
    #pragma unroll
    for (int kc = 0; kc < 4; ++kc) {
        Bf[kc][0] = *(const short8*)(WtPr + (w * 32 + lr) * 128 + kc * 32 + lg * 8);
        Bf[kc][1] = *(const short8*)(WtPr + (w * 32 + lr + 16) * 128 + kc * 32 + lg * 8);
    }
    int c0 = w * 32 + lr, c1 = c0 + 16;
    unsigned int gw = fbp[(size_t)(NP + NV) * 64 + w * 16 + lr];
    float base0 = 0.25f * bPr[c0] + bflo(gw);
    float base1 = 0.25f * bPr[c1] + bfhi(gw);
    const unsigned int* pfp = fbp;
    const unsigned int* vfp = fbp + (size_t)NP * 64;
    for (int tile = blockIdx.x; tile < ntiles; tile += gridDim.x) {
        int e0 = tile * 128;
        int vrows = min(128, nnz - e0);
        stage_f32_cvt_nt(values + (size_t)e0 * D, vrows, Al, t);
        if (t < 128) pI[t] = (t < vrows) ? point_idx[e0 + t] : 0;
        else { int u = t - 128; vI[u] = (u < vrows) ? view_idx[e0 + u] : 0; }
        __syncthreads();
        f32x4 acc[8][2] = {};
        #pragma unroll
        for (int kc = 0; kc < 4; ++kc) {
            int kb = kc * 64 + lg * 16;
            #pragma unroll
            for (int m = 0; m < 8; ++m) {
                int row = m * 16 + lr;
                short8 a = *(const short8*)&Al[((row * 256 + kb) ^ ((row & 7) << 4)) >> 1];
                acc[m][0] = __builtin_amdgcn_mfma_f32_16x16x32_bf16(a, Bf[kc][0], acc[m][0], 0, 0, 0);
                acc[m][1] = __builtin_amdgcn_mfma_f32_16x16x32_bf16(a, Bf[kc][1], acc[m][1], 0, 0, 0);
            }
        }
        #pragma unroll
        for (int m = 0; m < 8; ++m)
            #pragma unroll
            for (int r = 0; r < 4; ++r) {
                int row = m * 16 + lg * 4 + r;
                if (row < vrows) {
                    int p = pI[row], vv = vI[row];
                    unsigned int pu = pfp[(size_t)p * 64 + w * 16 + lr];
                    unsigned int vu = vfp[(size_t)vv * 64 + w * 16 + lr];
                    size_t o = (size_t)(e0 + row) * D;
                    ntst(&out[o + c0], acc[m][0][r] * 0.25f + base0 + bflo(pu) + bflo(vu));
                    ntst(&out[o + c1], acc[m][1][r] * 0.25f + base1 + bfhi(pu) + bfhi(vu));
                }
            }
        __syncthreads();   // protect Al/pI/vI before next tile
    }
}

extern "C" void kernel_launch(void* const* d_in, const int* in_sizes, int n_in,
                              void* d_out, int out_size, void* d_ws, size_t ws_size,
                              hipStream_t stream)
{
    const float* values    = (const float*)d_in[0];
    const int*   view_idx  = (const int*)d_in[1];
    const int*   point_idx = (const int*)d_in[2];
    const float* W_sp   = (const float*)d_in[5];
    const float* b_sp   = (const float*)d_in[6];
    const float* W_view = (const float*)d_in[7];
    const float* b_view = (const float*)d_in[8];
    const float* W_glob = (const float*)d_in[9];
    const float* b_glob = (const float*)d_in[10];
    const float* W_proj = (const float*)d_in[11];
    const float* b_proj = (const float*)d_in[12];
    int nnz = in_sizes[1];
    int ntiles = (nnz + 127) / 128;

    // ws: [gs|Cp|Cv](memset) | bsum|bbase|Bp|Bv | vlist | Wt4 | mbuf | fbp | vbuf16
    char* w = (char*)d_ws;
    float* gs = (float*)w;                          w += 128 * 4;
    int* Cp   = (int*)w;                            w += (size_t)NP * 4;
    int* Cv   = (int*)w;                            w += (size_t)NV * 4;
    size_t zero_bytes = (size_t)(w - (char*)d_ws);
    int* bsum = (int*)w;                            w += 64 * 4;
    int* bbase = (int*)w;                           w += 64 * 4;
    int* Bp   = (int*)w;                            w += (size_t)NP * 4;
    int* Bv   = (int*)w;                            w += (size_t)NV * 4;
    int* vlist = (int*)w;                           w += (size_t)nnz * 4;
    unsigned short* Wt4 = (unsigned short*)w;       w += (size_t)4 * 16384 * 2;
    unsigned int* mbuf = (unsigned int*)w;          w += (size_t)(NP + NV) * 64 * 4;
    unsigned int* fbp = (unsigned int*)w;           w += (size_t)(NP + NV + 1) * 64 * 4;
    unsigned int* vbuf16 = (unsigned int*)w;        w += (size_t)ntiles * 128 * 64 * 4;

    hipMemsetAsync(d_ws, 0, zero_bytes, stream);

    hipLaunchKernelGGL(k_prep, dim3(4), dim3(256), 0, stream,
                       W_sp, W_view, W_glob, W_proj, Wt4);
    hipLaunchKernelGGL(k_count, dim3(1024), dim3(256), 0, stream,
                       view_idx, point_idx, Cp, Cv, nnz);
    hipLaunchKernelGGL(k_scanA, dim3(64), dim3(256), 0, stream, Cp, bsum);
    hipLaunchKernelGGL(k_scanB, dim3(1), dim3(256), 0, stream, bsum, bbase, Cv, Bv);
    hipLaunchKernelGGL(k_scanC, dim3(64), dim3(256), 0, stream, Cp, Bp, bbase);
    hipLaunchKernelGGL(k_scatter_cvt, dim3(2048), dim3(256), 0, stream,
                       values, view_idx, point_idx, Cp, Cv, vlist, vbuf16, nnz);
    hipLaunchKernelGGL(k_psum, dim3(2048), dim3(256), 0, stream,
                       vbuf16, Bp, Cp, mbuf);
    hipLaunchKernelGGL(k_vsum, dim3(NV), dim3(512), 0, stream,
                       vbuf16, vlist, Bv, Cv, mbuf, gs);
    hipLaunchKernelGGL(k_featgemm, dim3(521), dim3(256), 0, stream,
                       mbuf, Wt4, b_sp, b_view, b_glob, gs, 1.f / (float)nnz, fbp);
    hipLaunchKernelGGL(k_proj, dim3(2048), dim3(256), 0, stream,
                       values, point_idx, view_idx, Wt4 + (size_t)3 * 16384, b_proj, fbp,
                       (float*)d_out, nnz, ntiles);
}